// Round 1
// baseline (2413.898 us; speedup 1.0000x reference)
//
#include <hip/hip_runtime.h>
#include <cstdint>
#include <cstddef>

#define NN 8192
#define NDRUG 2048
#define NMETA 6144
#define ETR 131072
#define EVL 32768
#define ETOT 163840
#define KC 8

typedef __attribute__((ext_vector_type(8))) short bf16x8;
typedef __attribute__((ext_vector_type(4))) float f32x4;

__device__ __forceinline__ float bf2f(unsigned short s) {
  return __uint_as_float(((unsigned)s) << 16);
}
__device__ __forceinline__ unsigned short f2bf_rne(float f) {
  unsigned u = __float_as_uint(f);
  unsigned r = u + 0x7fffu + ((u >> 16) & 1u);
  return (unsigned short)(r >> 16);
}
__device__ __forceinline__ float gelu_tanh(float x) {
  float u = 0.7978845608028654f * (x + 0.044715f * x * x * x);
  return 0.5f * x * (1.0f + tanhf(u));
}
__device__ __forceinline__ float rsum32(float v) {
#pragma unroll
  for (int m = 16; m >= 1; m >>= 1) v += __shfl_xor(v, m, 32);
  return v;
}

// ---------------- metapath encoder: one node per 128 threads, 2 nodes/block ----
template <int FIN>
__global__ __launch_bounds__(256) void enc_kernel(
    const float* __restrict__ x, int count, float* __restrict__ out,
    int out_stride, int out_row_off, int out_col_off,
    const float* __restrict__ Wemb, const float* __restrict__ bemb,
    const float* __restrict__ l1s, const float* __restrict__ l1b,
    const float* __restrict__ Wq, const float* __restrict__ bq,
    const float* __restrict__ Wk, const float* __restrict__ bk,
    const float* __restrict__ Wv, const float* __restrict__ bv,
    const float* __restrict__ Wo, const float* __restrict__ bo,
    const float* __restrict__ l2s, const float* __restrict__ l2b,
    const float* __restrict__ Wf1, const float* __restrict__ bf1,
    const float* __restrict__ Wf2, const float* __restrict__ bf2,
    const float* __restrict__ fs, const float* __restrict__ fb,
    const float* __restrict__ Wa, const float* __restrict__ ba) {
  __shared__ float xb[2][4 * FIN];
  __shared__ float yb[2][128];
  __shared__ float qb[2][128];
  __shared__ float kb[2][128];
  __shared__ float vb[2][128];
  __shared__ float ab[2][64];
  __shared__ float hb[2][256];
  __shared__ float lg[2][3];

  const int tid = threadIdx.x;
  const int tn = tid >> 7;
  const int tl = tid & 127;
  const int p = tl >> 5;
  const int d = tl & 31;
  const int node = blockIdx.x * 2 + tn;
  const bool active = node < count;
  const int nc = active ? node : 0;

  const float* xp = x + (size_t)nc * (4 * FIN);
  for (int i = tl; i < 4 * FIN; i += 128) xb[tn][i] = xp[i];
  __syncthreads();

  float tv = bemb[d];
  for (int k = 0; k < FIN; ++k) tv = fmaf(xb[tn][p * FIN + k], Wemb[k * 32 + d], tv);

#pragma unroll
  for (int l = 0; l < 2; ++l) {
    {  // LN1 -> yb
      float mu = rsum32(tv) * (1.f / 32.f);
      float dv = tv - mu;
      float var = rsum32(dv * dv) * (1.f / 32.f);
      yb[tn][tl] = dv * rsqrtf(var + 1e-5f) * l1s[l * 32 + d] + l1b[l * 32 + d];
    }
    __syncthreads();
    {  // QKV
      float aq = bq[l * 32 + d], ak = bk[l * 32 + d], av = bv[l * 32 + d];
      const float* wq = Wq + l * 1024 + d;
      const float* wk = Wk + l * 1024 + d;
      const float* wv = Wv + l * 1024 + d;
      for (int k = 0; k < 32; ++k) {
        float yk = yb[tn][p * 32 + k];
        aq = fmaf(yk, wq[k * 32], aq);
        ak = fmaf(yk, wk[k * 32], ak);
        av = fmaf(yk, wv[k * 32], av);
      }
      qb[tn][tl] = aq; kb[tn][tl] = ak; vb[tn][tl] = av;
    }
    __syncthreads();
    if (tl < 64) {  // scores + softmax, first wave of node
      int h = tl >> 4, qi = (tl >> 2) & 3, kj = tl & 3;
      float s = 0.f;
#pragma unroll
      for (int dd = 0; dd < 8; ++dd)
        s = fmaf(qb[tn][qi * 32 + h * 8 + dd], kb[tn][kj * 32 + h * 8 + dd], s);
      s *= 0.35355339059327373f;
      float mx = fmaxf(s, __shfl_xor(s, 1, 4));
      mx = fmaxf(mx, __shfl_xor(mx, 2, 4));
      float e = __expf(s - mx);
      float sm = e + __shfl_xor(e, 1, 4);
      sm += __shfl_xor(sm, 2, 4);
      ab[tn][tl] = e / sm;
    }
    __syncthreads();
    {  // ctx -> qb (reuse)
      int h = d >> 3;
      float c = 0.f;
#pragma unroll
      for (int j = 0; j < 4; ++j)
        c = fmaf(ab[tn][h * 16 + p * 4 + j], vb[tn][j * 32 + d], c);
      __syncthreads();
      qb[tn][tl] = c;
    }
    __syncthreads();
    {  // Wo + residual
      float o = bo[l * 32 + d];
      const float* wo = Wo + l * 1024 + d;
      for (int k = 0; k < 32; ++k) o = fmaf(qb[tn][p * 32 + k], wo[k * 32], o);
      tv += o;
    }
    __syncthreads();
    {  // LN2 -> yb
      float mu = rsum32(tv) * (1.f / 32.f);
      float dv = tv - mu;
      float var = rsum32(dv * dv) * (1.f / 32.f);
      yb[tn][tl] = dv * rsqrtf(var + 1e-5f) * l2s[l * 32 + d] + l2b[l * 32 + d];
    }
    __syncthreads();
    {  // FFN up + gelu
      float a1 = bf1[l * 64 + d], a2 = bf1[l * 64 + 32 + d];
      const float* wf = Wf1 + (size_t)l * 32 * 64;
      for (int k = 0; k < 32; ++k) {
        float yk = yb[tn][p * 32 + k];
        a1 = fmaf(yk, wf[k * 64 + d], a1);
        a2 = fmaf(yk, wf[k * 64 + 32 + d], a2);
      }
      hb[tn][p * 64 + d] = gelu_tanh(a1);
      hb[tn][p * 64 + 32 + d] = gelu_tanh(a2);
    }
    __syncthreads();
    {  // FFN down + residual
      float f = bf2[l * 32 + d];
      const float* wf = Wf2 + (size_t)l * 64 * 32 + d;
      for (int c = 0; c < 64; ++c) f = fmaf(hb[tn][p * 64 + c], wf[c * 32], f);
      tv += f;
    }
    __syncthreads();
  }
  {  // final LN -> yb
    float mu = rsum32(tv) * (1.f / 32.f);
    float dv = tv - mu;
    float var = rsum32(dv * dv) * (1.f / 32.f);
    yb[tn][tl] = dv * rsqrtf(var + 1e-5f) * fs[d] + fb[d];
  }
  __syncthreads();
  if (p >= 1) {  // neighbor attention logits
    float val = yb[tn][d] * Wa[d] + yb[tn][p * 32 + d] * Wa[32 + d];
#pragma unroll
    for (int m = 16; m >= 1; m >>= 1) val += __shfl_xor(val, m, 32);
    if (d == 0) lg[tn][p - 1] = val + ba[0];
  }
  __syncthreads();
  if (p == 0 && active) {
    float l0 = lg[tn][0], l1v = lg[tn][1], l2v = lg[tn][2];
    float mx = fmaxf(l0, fmaxf(l1v, l2v));
    float e0 = __expf(l0 - mx), e1 = __expf(l1v - mx), e2 = __expf(l2v - mx);
    float inv = 1.f / (e0 + e1 + e2);
    float r = yb[tn][d] +
              (e0 * yb[tn][32 + d] + e1 * yb[tn][64 + d] + e2 * yb[tn][96 + d]) * inv;
    out[(size_t)(out_row_off + node) * out_stride + out_col_off + d] = r;
  }
}

// ---------------- adjacency hop: part[kc] += A[rows, kslice] @ X ---------------
// A fp32 row-major; Xt = [2][64][8192] bf16 (hi,lo), transposed X.
__global__ __launch_bounds__(256) void hop_matmul(
    const float* __restrict__ A, const unsigned short* __restrict__ Xt,
    float* __restrict__ part) {
  const int w = threadIdx.x >> 6;
  const int lane = threadIdx.x & 63;
  const int quad = lane >> 4;
  const int mr = lane & 15;
  const int rg = blockIdx.x >> 3;  // /KC
  const int kc = blockIdx.x & (KC - 1);
  const int m0 = rg * 64 + w * 16;
  const int kbase = kc * (NN / KC);

  const float* ap = A + (size_t)(m0 + mr) * NN + kbase + quad * 8;
  const unsigned short* bp0 = Xt + (size_t)mr * NN + kbase + quad * 8;

  f32x4 acc[4];
#pragma unroll
  for (int i = 0; i < 4; ++i) acc[i] = (f32x4){0.f, 0.f, 0.f, 0.f};

  for (int ks = 0; ks < (NN / KC) / 32; ++ks) {
    f32x4 a01 = *(const f32x4*)(ap);
    f32x4 a23 = *(const f32x4*)(ap + 4);
    ap += 32;
    bf16x8 ahi, alo;
#pragma unroll
    for (int j = 0; j < 4; ++j) {
      unsigned short h0 = (unsigned short)(__float_as_uint(a01[j]) >> 16);
      ahi[j] = (short)h0;
      alo[j] = (short)f2bf_rne(a01[j] - bf2f(h0));
      unsigned short h1 = (unsigned short)(__float_as_uint(a23[j]) >> 16);
      ahi[4 + j] = (short)h1;
      alo[4 + j] = (short)f2bf_rne(a23[j] - bf2f(h1));
    }
    const unsigned short* bp = bp0 + (size_t)ks * 32;
#pragma unroll
    for (int ct = 0; ct < 4; ++ct) {
      bf16x8 bhi = *(const bf16x8*)(bp + (size_t)ct * 16 * NN);
      bf16x8 blo = *(const bf16x8*)(bp + (size_t)ct * 16 * NN + (size_t)64 * NN);
      acc[ct] = __builtin_amdgcn_mfma_f32_16x16x32_bf16(ahi, bhi, acc[ct], 0, 0, 0);
      acc[ct] = __builtin_amdgcn_mfma_f32_16x16x32_bf16(alo, bhi, acc[ct], 0, 0, 0);
      acc[ct] = __builtin_amdgcn_mfma_f32_16x16x32_bf16(ahi, blo, acc[ct], 0, 0, 0);
    }
  }
  float* pp = part + ((size_t)kc * NN + m0) * 64;
#pragma unroll
  for (int r = 0; r < 4; ++r) {
    int row = quad * 4 + r;
    pp[row * 64 + 0 + mr] = acc[0][r];
    pp[row * 64 + 16 + mr] = acc[1][r];
    pp[row * 64 + 32 + mr] = acc[2][r];
    pp[row * 64 + 48 + mr] = acc[3][r];
  }
}

// sum KC partials -> feats slot (fp32) + next hop's transposed hi/lo bf16 X
__global__ __launch_bounds__(256) void hop_finalize(
    const float* __restrict__ part, float* __restrict__ feats,
    unsigned short* __restrict__ Xt) {
  __shared__ float t[64][65];
  const int m0 = blockIdx.x * 64;
  const int tid = threadIdx.x;
#pragma unroll
  for (int it = 0; it < 16; ++it) {
    int idx = it * 256 + tid;
    int lm = idx >> 6, ln = idx & 63;
    size_t o = (size_t)(m0 + lm) * 64 + ln;
    float v = 0.f;
#pragma unroll
    for (int kc = 0; kc < KC; ++kc) v += part[(size_t)kc * NN * 64 + o];
    feats[(size_t)(m0 + lm) * 256 + ln] = v;
    t[lm][ln] = v;
  }
  __syncthreads();
#pragma unroll
  for (int it = 0; it < 16; ++it) {
    int idx = it * 256 + tid;
    int mm = idx & 63, nn = idx >> 6;
    float v = t[mm][nn];
    unsigned short h = (unsigned short)(__float_as_uint(v) >> 16);
    Xt[(size_t)nn * NN + m0 + mm] = h;
    Xt[(size_t)64 * NN + (size_t)nn * NN + m0 + mm] = f2bf_rne(v - bf2f(h));
  }
}

// dm -> feats slot0 (both chains) + Xt0
__global__ __launch_bounds__(256) void dm_to_xt(
    const float* __restrict__ dm, float* __restrict__ upf, float* __restrict__ dnf,
    unsigned short* __restrict__ Xt) {
  __shared__ float t[64][65];
  const int m0 = blockIdx.x * 64;
  const int tid = threadIdx.x;
#pragma unroll
  for (int it = 0; it < 16; ++it) {
    int idx = it * 256 + tid;
    int lm = idx >> 6, ln = idx & 63;
    float v = dm[(size_t)(m0 + lm) * 64 + ln];
    upf[(size_t)(m0 + lm) * 256 + ln] = v;
    dnf[(size_t)(m0 + lm) * 256 + ln] = v;
    t[lm][ln] = v;
  }
  __syncthreads();
#pragma unroll
  for (int it = 0; it < 16; ++it) {
    int idx = it * 256 + tid;
    int mm = idx & 63, nn = idx >> 6;
    float v = t[mm][nn];
    unsigned short h = (unsigned short)(__float_as_uint(v) >> 16);
    Xt[(size_t)nn * NN + m0 + mm] = h;
    Xt[(size_t)64 * NN + (size_t)nn * NN + m0 + mm] = f2bf_rne(v - bf2f(h));
  }
}

// ---------------- semantic attention --------------------------------------
__global__ void zero_acc(float* acc) {
  if (threadIdx.x < 4) acc[threadIdx.x] = 0.f;
}

__global__ __launch_bounds__(256) void sem_reduce(
    const float* __restrict__ up, const float* __restrict__ dn,
    const float* __restrict__ Ws, const float* __restrict__ bs,
    const float* __restrict__ qs, float* __restrict__ acc) {
  __shared__ float sacc[4];
  if (threadIdx.x < 4) sacc[threadIdx.x] = 0.f;
  __syncthreads();
  const int wv = threadIdx.x >> 6;
  const int lane = threadIdx.x & 63;
  const int r = blockIdx.x * 4 + wv;
  const int src = lane >> 5;
  const int d = lane & 31;
  const float* row = (src ? dn : up) + (size_t)r * 32;
  float rv = row[d];
  float a = bs[d];
  for (int k = 0; k < 32; ++k) a = fmaf(__shfl(rv, k, 32), Ws[k * 32 + d], a);
  float w = tanhf(a) * qs[d];
#pragma unroll
  for (int m = 16; m >= 1; m >>= 1) w += __shfl_xor(w, m, 32);
  int g = (r < NDRUG) ? 0 : 1;
  if (d == 0) atomicAdd(&sacc[g * 2 + src], w);
  __syncthreads();
  if (threadIdx.x < 4) atomicAdd(&acc[threadIdx.x], sacc[threadIdx.x]);
}

__global__ __launch_bounds__(256) void sem_combine(
    const float* __restrict__ up, const float* __restrict__ dn,
    const float* __restrict__ acc, float* __restrict__ drug, float* __restrict__ meta) {
  int idx = blockIdx.x * 256 + threadIdx.x;
  int r = idx >> 5;
  int g = (r < NDRUG) ? 0 : 1;
  float cnt = g ? (float)NMETA : (float)NDRUG;
  float w0 = acc[g * 2 + 0] / cnt, w1 = acc[g * 2 + 1] / cnt;
  float mx = fmaxf(w0, w1);
  float e0 = __expf(w0 - mx), e1 = __expf(w1 - mx);
  float inv = 1.f / (e0 + e1);
  float v = (e0 * inv) * up[idx] + (e1 * inv) * dn[idx];
  if (g == 0) drug[idx] = v;
  else meta[idx - NDRUG * 32] = v;
}

// ---------------- edge MLP --------------------------------------------------
__global__ __launch_bounds__(128) void pdpm_kernel(
    const float* __restrict__ drug, const float* __restrict__ meta,
    const float* __restrict__ Wm1, const float* __restrict__ bm1,
    float* __restrict__ Pd, float* __restrict__ Pm) {
  int row = blockIdx.x;
  int j = threadIdx.x;
  const float* src;
  const float* w;
  float* dst;
  float a;
  if (row < NDRUG) {
    src = drug + (size_t)row * 32; dst = Pd + (size_t)row * 128;
    w = Wm1; a = bm1[j];
  } else {
    src = meta + (size_t)(row - NDRUG) * 32; dst = Pm + (size_t)(row - NDRUG) * 128;
    w = Wm1 + 32 * 128; a = 0.f;
  }
#pragma unroll
  for (int k = 0; k < 32; ++k) a = fmaf(src[k], w[k * 128 + j], a);
  dst[j] = a;
}

__global__ __launch_bounds__(256) void edge_mlp(
    const int* __restrict__ tr, const int* __restrict__ vl,
    const float* __restrict__ Pd, const float* __restrict__ Pm,
    const float* __restrict__ Wm2, const float* __restrict__ bm2,
    const float* __restrict__ Wm3, const float* __restrict__ bm3,
    float* __restrict__ out) {
  const int wv = threadIdx.x >> 6;
  const int lane = threadIdx.x & 63;
  const int e = blockIdx.x * 4 + wv;
  int e0, e1;
  if (e < ETR) { e0 = tr[e]; e1 = tr[ETR + e]; }
  else { int q = e - ETR; e0 = vl[q]; e1 = vl[EVL + q]; }
  const float* pd = Pd + (size_t)e0 * 128;
  const float* pm = Pm + (size_t)e1 * 128;
  float h1a = fmaxf(pd[lane] + pm[lane], 0.f);
  float h1b = fmaxf(pd[64 + lane] + pm[64 + lane], 0.f);
  float h2 = bm2[lane];
  for (int k = 0; k < 64; ++k) {
    h2 = fmaf(__shfl(h1a, k, 64), Wm2[k * 64 + lane], h2);
    h2 = fmaf(__shfl(h1b, k, 64), Wm2[(64 + k) * 64 + lane], h2);
  }
  h2 = fmaxf(h2, 0.f);
  float o0 = h2 * Wm3[lane * 3 + 0];
  float o1 = h2 * Wm3[lane * 3 + 1];
  float o2 = h2 * Wm3[lane * 3 + 2];
#pragma unroll
  for (int m = 32; m >= 1; m >>= 1) {
    o0 += __shfl_xor(o0, m, 64);
    o1 += __shfl_xor(o1, m, 64);
    o2 += __shfl_xor(o2, m, 64);
  }
  if (lane == 0) {
    out[(size_t)e * 3 + 0] = o0 + bm3[0];
    out[(size_t)e * 3 + 1] = o1 + bm3[1];
    out[(size_t)e * 3 + 2] = o2 + bm3[2];
  }
}

// ---------------- host ------------------------------------------------------
extern "C" void kernel_launch(void* const* d_in, const int* in_sizes, int n_in,
                              void* d_out, int out_size, void* d_ws, size_t ws_size,
                              hipStream_t stream) {
  const float* A_dn = (const float*)d_in[0];
  const float* A_up = (const float*)d_in[1];
  const float* xDrDi = (const float*)d_in[2];
  const float* xDrG = (const float*)d_in[3];
  const float* xMDi = (const float*)d_in[4];
  const float* xMG = (const float*)d_in[5];
  const float* W80 = (const float*)d_in[6];
  const float* b80 = (const float*)d_in[7];
  const float* W64 = (const float*)d_in[8];
  const float* b64 = (const float*)d_in[9];
  const float* l1s = (const float*)d_in[10];
  const float* l1b = (const float*)d_in[11];
  const float* Wq = (const float*)d_in[12];
  const float* bq = (const float*)d_in[13];
  const float* Wk = (const float*)d_in[14];
  const float* bk = (const float*)d_in[15];
  const float* Wv = (const float*)d_in[16];
  const float* bv = (const float*)d_in[17];
  const float* Wo = (const float*)d_in[18];
  const float* bo = (const float*)d_in[19];
  const float* l2s = (const float*)d_in[20];
  const float* l2b = (const float*)d_in[21];
  const float* Wf1 = (const float*)d_in[22];
  const float* bf1 = (const float*)d_in[23];
  const float* Wf2 = (const float*)d_in[24];
  const float* bf2 = (const float*)d_in[25];
  const float* fs = (const float*)d_in[26];
  const float* fb = (const float*)d_in[27];
  const float* Wa = (const float*)d_in[28];
  const float* ba = (const float*)d_in[29];
  const float* Ws = (const float*)d_in[30];
  const float* bs = (const float*)d_in[31];
  const float* qs = (const float*)d_in[32];
  const float* Wm1 = (const float*)d_in[33];
  const float* bm1 = (const float*)d_in[34];
  const float* Wm2 = (const float*)d_in[35];
  const float* bm2 = (const float*)d_in[36];
  const float* Wm3 = (const float*)d_in[37];
  const float* bm3 = (const float*)d_in[38];
  const int* tre = (const int*)d_in[39];
  const int* vle = (const int*)d_in[40];
  (void)in_sizes; (void)n_in; (void)out_size; (void)ws_size;

  unsigned char* ws = (unsigned char*)d_ws;
  const size_t MB = 1024 * 1024;
  float* dm = (float*)(ws + 0);                       // 2 MB
  float* upf = (float*)(ws + 2 * MB);                 // 8 MB (8192,4,64)
  float* dnf = (float*)(ws + 10 * MB);                // 8 MB
  unsigned short* xt0 = (unsigned short*)(ws + 18 * MB);   // 2 MB each (hi+lo)
  unsigned short* xtUa = (unsigned short*)(ws + 20 * MB);
  unsigned short* xtUb = (unsigned short*)(ws + 22 * MB);
  unsigned short* xtDa = (unsigned short*)(ws + 24 * MB);
  unsigned short* xtDb = (unsigned short*)(ws + 26 * MB);
  float* part = (float*)(ws + 28 * MB);               // KC*2 MB = 16 MB
  float* up_out = (float*)(ws + 44 * MB);             // 1 MB
  float* dn_out = (float*)(ws + 45 * MB);             // 1 MB
  float* acc = (float*)(ws + 46 * MB);                // 16 B
  float* drug = (float*)(ws + 46 * MB + 256);         // 256 KB
  float* meta = (float*)(ws + 46 * MB + 256 + 256 * 1024);  // 768 KB
  float* Pd = (float*)(ws + 48 * MB);                 // 1 MB
  float* Pm = (float*)(ws + 49 * MB);                 // 3 MB; total 52 MB

  // 1) four metapath encodings -> dm (concat layout)
  enc_kernel<80><<<1024, 256, 0, stream>>>(xDrDi, NDRUG, dm, 64, 0, 0,
      W80, b80, l1s, l1b, Wq, bq, Wk, bk, Wv, bv, Wo, bo, l2s, l2b,
      Wf1, bf1, Wf2, bf2, fs, fb, Wa, ba);
  enc_kernel<80><<<1024, 256, 0, stream>>>(xDrG, NDRUG, dm, 64, 0, 32,
      W80, b80, l1s, l1b, Wq, bq, Wk, bk, Wv, bv, Wo, bo, l2s, l2b,
      Wf1, bf1, Wf2, bf2, fs, fb, Wa, ba);
  enc_kernel<80><<<3072, 256, 0, stream>>>(xMDi, NMETA, dm, 64, NDRUG, 0,
      W80, b80, l1s, l1b, Wq, bq, Wk, bk, Wv, bv, Wo, bo, l2s, l2b,
      Wf1, bf1, Wf2, bf2, fs, fb, Wa, ba);
  enc_kernel<80><<<3072, 256, 0, stream>>>(xMG, NMETA, dm, 64, NDRUG, 32,
      W80, b80, l1s, l1b, Wq, bq, Wk, bk, Wv, bv, Wo, bo, l2s, l2b,
      Wf1, bf1, Wf2, bf2, fs, fb, Wa, ba);

  // 2) dm -> slot0 feats + Xt0
  dm_to_xt<<<128, 256, 0, stream>>>(dm, upf, dnf, xt0);

  // 3) hop chains
  hop_matmul<<<128 * KC, 256, 0, stream>>>(A_dn, xt0, part);
  hop_finalize<<<128, 256, 0, stream>>>(part, upf + 64, xtUa);
  hop_matmul<<<128 * KC, 256, 0, stream>>>(A_dn, xtUa, part);
  hop_finalize<<<128, 256, 0, stream>>>(part, upf + 128, xtUb);
  hop_matmul<<<128 * KC, 256, 0, stream>>>(A_dn, xtUb, part);
  hop_finalize<<<128, 256, 0, stream>>>(part, upf + 192, xtUa);

  hop_matmul<<<128 * KC, 256, 0, stream>>>(A_up, xt0, part);
  hop_finalize<<<128, 256, 0, stream>>>(part, dnf + 64, xtDa);
  hop_matmul<<<128 * KC, 256, 0, stream>>>(A_up, xtDa, part);
  hop_finalize<<<128, 256, 0, stream>>>(part, dnf + 128, xtDb);
  hop_matmul<<<128 * KC, 256, 0, stream>>>(A_up, xtDb, part);
  hop_finalize<<<128, 256, 0, stream>>>(part, dnf + 192, xtDa);

  // 4) encoders on hop features
  enc_kernel<64><<<4096, 256, 0, stream>>>(upf, NN, up_out, 32, 0, 0,
      W64, b64, l1s, l1b, Wq, bq, Wk, bk, Wv, bv, Wo, bo, l2s, l2b,
      Wf1, bf1, Wf2, bf2, fs, fb, Wa, ba);
  enc_kernel<64><<<4096, 256, 0, stream>>>(dnf, NN, dn_out, 32, 0, 0,
      W64, b64, l1s, l1b, Wq, bq, Wk, bk, Wv, bv, Wo, bo, l2s, l2b,
      Wf1, bf1, Wf2, bf2, fs, fb, Wa, ba);

  // 5) semantic attention -> drug/meta embeddings
  zero_acc<<<1, 64, 0, stream>>>(acc);
  sem_reduce<<<2048, 256, 0, stream>>>(up_out, dn_out, Ws, bs, qs, acc);
  sem_combine<<<1024, 256, 0, stream>>>(up_out, dn_out, acc, drug, meta);

  // 6) edge MLP
  pdpm_kernel<<<NN, 128, 0, stream>>>(drug, meta, Wm1, bm1, Pd, Pm);
  edge_mlp<<<ETOT / 4, 256, 0, stream>>>(tre, vle, Pd, Pm, Wm2, bm2, Wm3, bm3,
                                         (float*)d_out);
}

// Round 2
// 1785.525 us; speedup vs baseline: 1.3519x; 1.3519x over previous
//
#include <hip/hip_runtime.h>
#include <cstdint>
#include <cstddef>

#define NN 8192
#define NDRUG 2048
#define NMETA 6144
#define ETR 131072
#define EVL 32768
#define ETOT 163840
#define KC 8

typedef __attribute__((ext_vector_type(8))) short bf16x8;
typedef __attribute__((ext_vector_type(4))) float f32x4;

__device__ __forceinline__ float bf2f(unsigned short s) {
  return __uint_as_float(((unsigned)s) << 16);
}
__device__ __forceinline__ unsigned short f2bf_rne(float f) {
  unsigned u = __float_as_uint(f);
  unsigned r = u + 0x7fffu + ((u >> 16) & 1u);
  return (unsigned short)(r >> 16);
}
__device__ __forceinline__ float gelu_tanh(float x) {
  float u = 0.7978845608028654f * (x + 0.044715f * x * x * x);
  return 0.5f * x * (1.0f + tanhf(u));
}
__device__ __forceinline__ float rsum16(float v) {
#pragma unroll
  for (int m = 8; m >= 1; m >>= 1) v += __shfl_xor(v, m, 16);
  return v;
}
// wave-local LDS fence: drain lgkm + stop compiler reordering
__device__ __forceinline__ void wsync() {
  asm volatile("s_waitcnt lgkmcnt(0)" ::: "memory");
}

// ================= metapath encoder v2: one WAVE per node ====================
// lane = p*16 + dh; lane owns dims d0=dh, d1=dh+16. Weights bf16 in LDS,
// staged once per 512-thread block; activations fp32 in per-wave LDS scratch.
// No __syncthreads in the node loop (wave-synchronous).
template <int PHASE>
__global__ __launch_bounds__(512, 4) void enc2_kernel(
    const float* __restrict__ x0, const float* __restrict__ x1,
    const float* __restrict__ x2, const float* __restrict__ x3,
    float* __restrict__ out0, float* __restrict__ out1,
    const float* __restrict__ Wemb, const float* __restrict__ bemb,
    const float* __restrict__ l1s, const float* __restrict__ l1b,
    const float* __restrict__ Wq, const float* __restrict__ bq,
    const float* __restrict__ Wk, const float* __restrict__ bk,
    const float* __restrict__ Wv, const float* __restrict__ bv,
    const float* __restrict__ Wo, const float* __restrict__ bo,
    const float* __restrict__ l2s, const float* __restrict__ l2b,
    const float* __restrict__ Wf1, const float* __restrict__ bf1,
    const float* __restrict__ Wf2, const float* __restrict__ bf2,
    const float* __restrict__ fs, const float* __restrict__ fb,
    const float* __restrict__ Wa) {
  constexpr int FIN = (PHASE == 0) ? 80 : 64;
  constexpr int FS = FIN + 1;
  constexpr int W_EM = FIN * 32;
  // bf16 weight arrays (LDS shorts)
  __shared__ unsigned short wsh[W_EM + 4 * 2048 + 2 * 4096];
  __shared__ float bsh[864];
  __shared__ float scr[8 * 648];

  unsigned short* wem = wsh;
  unsigned short* wqp = wsh + W_EM;
  unsigned short* wkp = wqp + 2048;
  unsigned short* wvp = wkp + 2048;
  unsigned short* wop = wvp + 2048;
  unsigned short* wf1s = wop + 2048;
  unsigned short* wf2s = wf1s + 4096;

  // bias offsets
  const int B_EM = 0, B_Q = 32, B_K = 96, B_V = 160, B_O = 224, B_F1 = 288,
            B_F2 = 416, B_L1S = 480, B_L1B = 544, B_L2S = 608, B_L2B = 672,
            B_FS = 736, B_FB = 768, B_WA = 800;

  const int tid = threadIdx.x;
  // ---- stage weights (bf16) + biases (fp32) ----
  for (int i = tid; i < W_EM; i += 512) {
    int k = i >> 5, d = i & 31;
    wem[k * 32 + ((d & 15) << 1) + (d >> 4)] = f2bf_rne(Wemb[i]);
  }
  for (int i = tid; i < 2048; i += 512) {
    int l = i >> 10, k = (i >> 5) & 31, d = i & 31;
    int o = (l * 32 + k) * 32 + ((d & 15) << 1) + (d >> 4);
    wqp[o] = f2bf_rne(Wq[i]);
    wkp[o] = f2bf_rne(Wk[i]);
    wvp[o] = f2bf_rne(Wv[i]);
    wop[o] = f2bf_rne(Wo[i]);
  }
  for (int i = tid; i < 4096; i += 512) {
    int l = i >> 11, k = (i >> 6) & 31, c = i & 63;
    wf1s[((l * 32 + k) * 16 + (c & 15)) * 4 + (c >> 4)] = f2bf_rne(Wf1[i]);
    int k2 = (i >> 5) & 63, d2 = i & 31;
    wf2s[((l * 64 + k2) * 16 + (d2 & 15)) * 2 + (d2 >> 4)] = f2bf_rne(Wf2[i]);
  }
  if (tid < 32) {
    bsh[B_EM + tid] = bemb[tid];
    bsh[B_FS + tid] = fs[tid];
    bsh[B_FB + tid] = fb[tid];
  }
  if (tid < 64) {
    bsh[B_Q + tid] = bq[tid];
    bsh[B_K + tid] = bk[tid];
    bsh[B_V + tid] = bv[tid];
    bsh[B_O + tid] = bo[tid];
    bsh[B_L1S + tid] = l1s[tid];
    bsh[B_L1B + tid] = l1b[tid];
    bsh[B_L2S + tid] = l2s[tid];
    bsh[B_L2B + tid] = l2b[tid];
    bsh[B_F2 + tid] = bf2[tid];
    bsh[B_WA + tid] = Wa[tid];
  }
  if (tid < 128) bsh[B_F1 + tid] = bf1[tid];
  __syncthreads();

  const int wid = tid >> 6;
  const int lane = tid & 63;
  const int p = lane >> 4;
  const int dh = lane & 15;
  const int d0 = dh, d1 = dh + 16;

  float* WS = scr + wid * 648;
  float* RA = WS;        // 512 floats: xs / qs,ks,vs,as / hs
  float* RY = WS + 512;  // 136 floats: ys / cs
  float* xs = RA;
  float* qs = RA;
  float* ks = RA + 132;
  float* vs = RA + 264;
  float* as_ = RA + 396;
  float* hs = RA;
  float* ys = RY;
  float* cs = RY;

  for (int ni = 0; ni < 4; ++ni) {
    int node = blockIdx.x * 32 + wid * 4 + ni;
    const float* xp;
    float* op;
    if (PHASE == 0) {
      if (node < 2048) { xp = x0 + (size_t)node * 320; op = out0 + (size_t)node * 64; }
      else if (node < 4096) { xp = x1 + (size_t)(node - 2048) * 320; op = out0 + (size_t)(node - 2048) * 64 + 32; }
      else if (node < 10240) { xp = x2 + (size_t)(node - 4096) * 320; op = out0 + (size_t)(2048 + node - 4096) * 64; }
      else { xp = x3 + (size_t)(node - 10240) * 320; op = out0 + (size_t)(2048 + node - 10240) * 64 + 32; }
    } else {
      if (node < 8192) { xp = x0 + (size_t)node * 256; op = out0 + (size_t)node * 32; }
      else { xp = x1 + (size_t)(node - 8192) * 256; op = out1 + (size_t)(node - 8192) * 32; }
    }
    // ---- stage x ----
    wsync();
#pragma unroll
    for (int i = lane; i < 4 * FIN; i += 64) {
      int r = i / FIN, c = i - r * FIN;
      xs[r * FS + c] = xp[i];
    }
    wsync();
    // ---- embed ----
    float t0 = bsh[B_EM + d0], t1 = bsh[B_EM + d1];
    for (int k = 0; k < FIN; ++k) {
      float xv = xs[p * FS + k];
      ushort2 w = *(const ushort2*)&wem[(k * 16 + dh) * 2];
      t0 = fmaf(xv, bf2f(w.x), t0);
      t1 = fmaf(xv, bf2f(w.y), t1);
    }
#pragma unroll
    for (int l = 0; l < 2; ++l) {
      // ---- LN1 ----
      float mu = rsum16(t0 + t1) * (1.f / 32.f);
      float a0 = t0 - mu, a1 = t1 - mu;
      float rsd = rsqrtf(rsum16(a0 * a0 + a1 * a1) * (1.f / 32.f) + 1e-5f);
      float y0 = a0 * rsd * bsh[B_L1S + l * 32 + d0] + bsh[B_L1B + l * 32 + d0];
      float y1 = a1 * rsd * bsh[B_L1S + l * 32 + d1] + bsh[B_L1B + l * 32 + d1];
      wsync();
      ys[p * 33 + dh] = y0;
      ys[p * 33 + 16 + dh] = y1;
      wsync();
      // ---- QKV ----
      float q0 = bsh[B_Q + l * 32 + d0], q1 = bsh[B_Q + l * 32 + d1];
      float kk0 = bsh[B_K + l * 32 + d0], kk1 = bsh[B_K + l * 32 + d1];
      float v0 = bsh[B_V + l * 32 + d0], v1 = bsh[B_V + l * 32 + d1];
#pragma unroll 8
      for (int k = 0; k < 32; ++k) {
        float yv = ys[p * 33 + k];
        int o = ((l * 32 + k) * 16 + dh) * 2;
        ushort2 a = *(const ushort2*)&wqp[o];
        ushort2 b = *(const ushort2*)&wkp[o];
        ushort2 c = *(const ushort2*)&wvp[o];
        q0 = fmaf(yv, bf2f(a.x), q0); q1 = fmaf(yv, bf2f(a.y), q1);
        kk0 = fmaf(yv, bf2f(b.x), kk0); kk1 = fmaf(yv, bf2f(b.y), kk1);
        v0 = fmaf(yv, bf2f(c.x), v0); v1 = fmaf(yv, bf2f(c.y), v1);
      }
      wsync();
      qs[p * 33 + dh] = q0; qs[p * 33 + 16 + dh] = q1;
      ks[p * 33 + dh] = kk0; ks[p * 33 + 16 + dh] = kk1;
      vs[p * 33 + dh] = v0; vs[p * 33 + 16 + dh] = v1;
      wsync();
      // ---- scores + softmax (lane = head*16 + qi*4 + kj) ----
      {
        int qi = (lane >> 2) & 3, kj = lane & 3, hh = p;
        float s = 0.f;
#pragma unroll
        for (int j = 0; j < 8; ++j)
          s = fmaf(qs[qi * 33 + hh * 8 + j], ks[kj * 33 + hh * 8 + j], s);
        s *= 0.35355339059327373f;
        float mx = fmaxf(s, __shfl_xor(s, 1, 4));
        mx = fmaxf(mx, __shfl_xor(mx, 2, 4));
        float e = __expf(s - mx);
        float den = e + __shfl_xor(e, 1, 4);
        den += __shfl_xor(den, 2, 4);
        as_[lane] = e / den;
      }
      wsync();
      // ---- ctx -> cs ----
      {
        int h0 = dh >> 3, h1 = 2 + (dh >> 3);
        float c0 = 0.f, c1 = 0.f;
#pragma unroll
        for (int j = 0; j < 4; ++j) {
          c0 = fmaf(as_[h0 * 16 + p * 4 + j], vs[j * 33 + dh], c0);
          c1 = fmaf(as_[h1 * 16 + p * 4 + j], vs[j * 33 + 16 + dh], c1);
        }
        cs[p * 33 + dh] = c0;
        cs[p * 33 + 16 + dh] = c1;
      }
      wsync();
      // ---- Wo + residual ----
      float o0 = bsh[B_O + l * 32 + d0], o1 = bsh[B_O + l * 32 + d1];
#pragma unroll 8
      for (int k = 0; k < 32; ++k) {
        float cv = cs[p * 33 + k];
        ushort2 w = *(const ushort2*)&wop[((l * 32 + k) * 16 + dh) * 2];
        o0 = fmaf(cv, bf2f(w.x), o0);
        o1 = fmaf(cv, bf2f(w.y), o1);
      }
      t0 += o0; t1 += o1;
      // ---- LN2 ----
      mu = rsum16(t0 + t1) * (1.f / 32.f);
      a0 = t0 - mu; a1 = t1 - mu;
      rsd = rsqrtf(rsum16(a0 * a0 + a1 * a1) * (1.f / 32.f) + 1e-5f);
      y0 = a0 * rsd * bsh[B_L2S + l * 32 + d0] + bsh[B_L2B + l * 32 + d0];
      y1 = a1 * rsd * bsh[B_L2S + l * 32 + d1] + bsh[B_L2B + l * 32 + d1];
      wsync();
      ys[p * 33 + dh] = y0;
      ys[p * 33 + 16 + dh] = y1;
      wsync();
      // ---- FFN1 + gelu ----
      float f0 = bsh[B_F1 + l * 64 + dh], f1 = bsh[B_F1 + l * 64 + 16 + dh];
      float f2v = bsh[B_F1 + l * 64 + 32 + dh], f3 = bsh[B_F1 + l * 64 + 48 + dh];
#pragma unroll 8
      for (int k = 0; k < 32; ++k) {
        float yv = ys[p * 33 + k];
        ushort4 w = *(const ushort4*)&wf1s[((l * 32 + k) * 16 + dh) * 4];
        f0 = fmaf(yv, bf2f(w.x), f0);
        f1 = fmaf(yv, bf2f(w.y), f1);
        f2v = fmaf(yv, bf2f(w.z), f2v);
        f3 = fmaf(yv, bf2f(w.w), f3);
      }
      wsync();
      hs[p * 65 + dh] = gelu_tanh(f0);
      hs[p * 65 + 16 + dh] = gelu_tanh(f1);
      hs[p * 65 + 32 + dh] = gelu_tanh(f2v);
      hs[p * 65 + 48 + dh] = gelu_tanh(f3);
      wsync();
      // ---- FFN2 + residual ----
      float g0 = bsh[B_F2 + l * 32 + d0], g1 = bsh[B_F2 + l * 32 + d1];
#pragma unroll 8
      for (int k = 0; k < 64; ++k) {
        float hv = hs[p * 65 + k];
        ushort2 w = *(const ushort2*)&wf2s[((l * 64 + k) * 16 + dh) * 2];
        g0 = fmaf(hv, bf2f(w.x), g0);
        g1 = fmaf(hv, bf2f(w.y), g1);
      }
      t0 += g0; t1 += g1;
    }
    // ---- final LN ----
    {
      float mu = rsum16(t0 + t1) * (1.f / 32.f);
      float a0 = t0 - mu, a1 = t1 - mu;
      float rsd = rsqrtf(rsum16(a0 * a0 + a1 * a1) * (1.f / 32.f) + 1e-5f);
      float y0 = a0 * rsd * bsh[B_FS + d0] + bsh[B_FB + d0];
      float y1 = a1 * rsd * bsh[B_FS + d1] + bsh[B_FB + d1];
      wsync();
      ys[p * 33 + dh] = y0;
      ys[p * 33 + 16 + dh] = y1;
      wsync();
    }
    // ---- neighbor attention + combine (ba cancels in softmax) ----
    {
      float part = ys[d0] * bsh[B_WA + d0] + ys[d1] * bsh[B_WA + d1] +
                   ys[p * 33 + d0] * bsh[B_WA + 32 + d0] +
                   ys[p * 33 + d1] * bsh[B_WA + 32 + d1];
      part = rsum16(part);
      float L1 = __shfl(part, 16, 64);
      float L2 = __shfl(part, 32, 64);
      float L3 = __shfl(part, 48, 64);
      float mx = fmaxf(L1, fmaxf(L2, L3));
      float e1 = __expf(L1 - mx), e2 = __expf(L2 - mx), e3 = __expf(L3 - mx);
      float inv = 1.f / (e1 + e2 + e3);
      if (p == 0) {
        float r0 = ys[d0] + (e1 * ys[33 + d0] + e2 * ys[66 + d0] + e3 * ys[99 + d0]) * inv;
        float r1 = ys[d1] + (e1 * ys[33 + d1] + e2 * ys[66 + d1] + e3 * ys[99 + d1]) * inv;
        op[d0] = r0;
        op[d1] = r1;
      }
      wsync();
    }
  }
}

// ---------------- adjacency hop: part[kc] += A[rows, kslice] @ X ---------------
__global__ __launch_bounds__(256) void hop_matmul(
    const float* __restrict__ A, const unsigned short* __restrict__ Xt,
    float* __restrict__ part) {
  const int w = threadIdx.x >> 6;
  const int lane = threadIdx.x & 63;
  const int quad = lane >> 4;
  const int mr = lane & 15;
  const int rg = blockIdx.x >> 3;
  const int kc = blockIdx.x & (KC - 1);
  const int m0 = rg * 64 + w * 16;
  const int kbase = kc * (NN / KC);

  const float* ap = A + (size_t)(m0 + mr) * NN + kbase + quad * 8;
  const unsigned short* bp0 = Xt + (size_t)mr * NN + kbase + quad * 8;

  f32x4 acc[4];
#pragma unroll
  for (int i = 0; i < 4; ++i) acc[i] = (f32x4){0.f, 0.f, 0.f, 0.f};

  for (int ks = 0; ks < (NN / KC) / 32; ++ks) {
    f32x4 a01 = *(const f32x4*)(ap);
    f32x4 a23 = *(const f32x4*)(ap + 4);
    ap += 32;
    bf16x8 ahi, alo;
#pragma unroll
    for (int j = 0; j < 4; ++j) {
      unsigned short h0 = (unsigned short)(__float_as_uint(a01[j]) >> 16);
      ahi[j] = (short)h0;
      alo[j] = (short)f2bf_rne(a01[j] - bf2f(h0));
      unsigned short h1 = (unsigned short)(__float_as_uint(a23[j]) >> 16);
      ahi[4 + j] = (short)h1;
      alo[4 + j] = (short)f2bf_rne(a23[j] - bf2f(h1));
    }
    const unsigned short* bp = bp0 + (size_t)ks * 32;
#pragma unroll
    for (int ct = 0; ct < 4; ++ct) {
      bf16x8 bhi = *(const bf16x8*)(bp + (size_t)ct * 16 * NN);
      bf16x8 blo = *(const bf16x8*)(bp + (size_t)ct * 16 * NN + (size_t)64 * NN);
      acc[ct] = __builtin_amdgcn_mfma_f32_16x16x32_bf16(ahi, bhi, acc[ct], 0, 0, 0);
      acc[ct] = __builtin_amdgcn_mfma_f32_16x16x32_bf16(alo, bhi, acc[ct], 0, 0, 0);
      acc[ct] = __builtin_amdgcn_mfma_f32_16x16x32_bf16(ahi, blo, acc[ct], 0, 0, 0);
    }
  }
  float* pp = part + ((size_t)kc * NN + m0) * 64;
#pragma unroll
  for (int r = 0; r < 4; ++r) {
    int row = quad * 4 + r;
    pp[row * 64 + 0 + mr] = acc[0][r];
    pp[row * 64 + 16 + mr] = acc[1][r];
    pp[row * 64 + 32 + mr] = acc[2][r];
    pp[row * 64 + 48 + mr] = acc[3][r];
  }
}

// sum KC partials -> feats slot (fp32) + next hop's transposed hi/lo bf16 X
__global__ __launch_bounds__(256) void hop_finalize(
    const float* __restrict__ part, float* __restrict__ feats,
    unsigned short* __restrict__ Xt) {
  __shared__ float t[64][65];
  const int m0 = blockIdx.x * 64;
  const int tid = threadIdx.x;
#pragma unroll
  for (int it = 0; it < 16; ++it) {
    int idx = it * 256 + tid;
    int lm = idx >> 6, ln = idx & 63;
    size_t o = (size_t)(m0 + lm) * 64 + ln;
    float v = 0.f;
#pragma unroll
    for (int kc = 0; kc < KC; ++kc) v += part[(size_t)kc * NN * 64 + o];
    feats[(size_t)(m0 + lm) * 256 + ln] = v;
    t[lm][ln] = v;
  }
  __syncthreads();
#pragma unroll
  for (int it = 0; it < 16; ++it) {
    int idx = it * 256 + tid;
    int mm = idx & 63, nn = idx >> 6;
    float v = t[mm][nn];
    unsigned short h = (unsigned short)(__float_as_uint(v) >> 16);
    Xt[(size_t)nn * NN + m0 + mm] = h;
    Xt[(size_t)64 * NN + (size_t)nn * NN + m0 + mm] = f2bf_rne(v - bf2f(h));
  }
}

// dm -> feats slot0 (both chains) + Xt0
__global__ __launch_bounds__(256) void dm_to_xt(
    const float* __restrict__ dm, float* __restrict__ upf, float* __restrict__ dnf,
    unsigned short* __restrict__ Xt) {
  __shared__ float t[64][65];
  const int m0 = blockIdx.x * 64;
  const int tid = threadIdx.x;
#pragma unroll
  for (int it = 0; it < 16; ++it) {
    int idx = it * 256 + tid;
    int lm = idx >> 6, ln = idx & 63;
    float v = dm[(size_t)(m0 + lm) * 64 + ln];
    upf[(size_t)(m0 + lm) * 256 + ln] = v;
    dnf[(size_t)(m0 + lm) * 256 + ln] = v;
    t[lm][ln] = v;
  }
  __syncthreads();
#pragma unroll
  for (int it = 0; it < 16; ++it) {
    int idx = it * 256 + tid;
    int mm = idx & 63, nn = idx >> 6;
    float v = t[mm][nn];
    unsigned short h = (unsigned short)(__float_as_uint(v) >> 16);
    Xt[(size_t)nn * NN + m0 + mm] = h;
    Xt[(size_t)64 * NN + (size_t)nn * NN + m0 + mm] = f2bf_rne(v - bf2f(h));
  }
}

// ---------------- semantic attention --------------------------------------
__global__ void zero_acc(float* acc) {
  if (threadIdx.x < 4) acc[threadIdx.x] = 0.f;
}

__global__ __launch_bounds__(256) void sem_reduce(
    const float* __restrict__ up, const float* __restrict__ dn,
    const float* __restrict__ Ws, const float* __restrict__ bs,
    const float* __restrict__ qs, float* __restrict__ acc) {
  __shared__ float sacc[4];
  if (threadIdx.x < 4) sacc[threadIdx.x] = 0.f;
  __syncthreads();
  const int wv = threadIdx.x >> 6;
  const int lane = threadIdx.x & 63;
  const int r = blockIdx.x * 4 + wv;
  const int src = lane >> 5;
  const int d = lane & 31;
  const float* row = (src ? dn : up) + (size_t)r * 32;
  float rv = row[d];
  float a = bs[d];
  for (int k = 0; k < 32; ++k) a = fmaf(__shfl(rv, k, 32), Ws[k * 32 + d], a);
  float w = tanhf(a) * qs[d];
#pragma unroll
  for (int m = 16; m >= 1; m >>= 1) w += __shfl_xor(w, m, 32);
  int g = (r < NDRUG) ? 0 : 1;
  if (d == 0) atomicAdd(&sacc[g * 2 + src], w);
  __syncthreads();
  if (threadIdx.x < 4) atomicAdd(&acc[threadIdx.x], sacc[threadIdx.x]);
}

__global__ __launch_bounds__(256) void sem_combine(
    const float* __restrict__ up, const float* __restrict__ dn,
    const float* __restrict__ acc, float* __restrict__ drug, float* __restrict__ meta) {
  int idx = blockIdx.x * 256 + threadIdx.x;
  int r = idx >> 5;
  int g = (r < NDRUG) ? 0 : 1;
  float cnt = g ? (float)NMETA : (float)NDRUG;
  float w0 = acc[g * 2 + 0] / cnt, w1 = acc[g * 2 + 1] / cnt;
  float mx = fmaxf(w0, w1);
  float e0 = __expf(w0 - mx), e1 = __expf(w1 - mx);
  float inv = 1.f / (e0 + e1);
  float v = (e0 * inv) * up[idx] + (e1 * inv) * dn[idx];
  if (g == 0) drug[idx] = v;
  else meta[idx - NDRUG * 32] = v;
}

// ---------------- edge MLP --------------------------------------------------
__global__ __launch_bounds__(128) void pdpm_kernel(
    const float* __restrict__ drug, const float* __restrict__ meta,
    const float* __restrict__ Wm1, const float* __restrict__ bm1,
    float* __restrict__ Pd, float* __restrict__ Pm) {
  int row = blockIdx.x;
  int j = threadIdx.x;
  const float* src;
  const float* w;
  float* dst;
  float a;
  if (row < NDRUG) {
    src = drug + (size_t)row * 32; dst = Pd + (size_t)row * 128;
    w = Wm1; a = bm1[j];
  } else {
    src = meta + (size_t)(row - NDRUG) * 32; dst = Pm + (size_t)(row - NDRUG) * 128;
    w = Wm1 + 32 * 128; a = 0.f;
  }
#pragma unroll
  for (int k = 0; k < 32; ++k) a = fmaf(src[k], w[k * 128 + j], a);
  dst[j] = a;
}

// edge MLP v2: 64 edges/block via MFMA. h1 (gather+relu) bf16 -> LDS A-tile,
// Wm2 bf16 -> LDS B (transposed), 16x16x32 mfma, h3 folded in C-layout.
__global__ __launch_bounds__(256, 4) void edge_mlp2(
    const int* __restrict__ tr, const int* __restrict__ vl,
    const float* __restrict__ Pd, const float* __restrict__ Pm,
    const float* __restrict__ Wm2, const float* __restrict__ bm2,
    const float* __restrict__ Wm3, const float* __restrict__ bm3,
    float* __restrict__ out) {
  __shared__ unsigned short Ah[64 * 136];
  __shared__ unsigned short WT[64 * 136];
  const int tid = threadIdx.x;
  const int lane = tid & 63;
  const int wid = tid >> 6;
  const int quad = lane >> 4;
  const int mr = lane & 15;

  // per-lane constants for the h2->h3 tail (cols nt*16+mr)
  float b2r[4], w3r[4][3];
#pragma unroll
  for (int nt = 0; nt < 4; ++nt) {
    int n = nt * 16 + mr;
    b2r[nt] = bm2[n];
    w3r[nt][0] = Wm3[n * 3 + 0];
    w3r[nt][1] = Wm3[n * 3 + 1];
    w3r[nt][2] = Wm3[n * 3 + 2];
  }
  float b3x = bm3[0], b3y = bm3[1], b3z = bm3[2];

  // stage Wm2 (transposed, bf16)
  for (int i = tid; i < 8192; i += 256) {
    int k = i >> 6, n = i & 63;
    WT[n * 136 + k] = f2bf_rne(Wm2[i]);
  }
  // stage A = relu(Pd[e0] + Pm[e1]) as bf16; thread t covers edge t>>2, quarter t&3
  {
    int e_loc = tid >> 2, kq = tid & 3;
    int eg = blockIdx.x * 64 + e_loc;
    int e0, e1;
    if (eg < ETR) { e0 = tr[eg]; e1 = tr[ETR + eg]; }
    else { e0 = vl[eg - ETR]; e1 = vl[EVL + eg - ETR]; }
    const float4* pd4 = (const float4*)(Pd + (size_t)e0 * 128 + kq * 32);
    const float4* pm4 = (const float4*)(Pm + (size_t)e1 * 128 + kq * 32);
    unsigned int* arow = (unsigned int*)&Ah[e_loc * 136 + kq * 32];
#pragma unroll
    for (int i = 0; i < 8; ++i) {
      float4 a = pd4[i], b = pm4[i];
      unsigned s0 = f2bf_rne(fmaxf(a.x + b.x, 0.f));
      unsigned s1 = f2bf_rne(fmaxf(a.y + b.y, 0.f));
      unsigned s2 = f2bf_rne(fmaxf(a.z + b.z, 0.f));
      unsigned s3 = f2bf_rne(fmaxf(a.w + b.w, 0.f));
      arow[i * 2 + 0] = s0 | (s1 << 16);
      arow[i * 2 + 1] = s2 | (s3 << 16);
    }
  }
  __syncthreads();

  const int m0 = wid * 16;
  f32x4 acc[4];
#pragma unroll
  for (int i = 0; i < 4; ++i) acc[i] = (f32x4){0.f, 0.f, 0.f, 0.f};
#pragma unroll
  for (int kt = 0; kt < 4; ++kt) {
    bf16x8 af = *(const bf16x8*)&Ah[(m0 + mr) * 136 + kt * 32 + quad * 8];
#pragma unroll
    for (int nt = 0; nt < 4; ++nt) {
      bf16x8 bf = *(const bf16x8*)&WT[(nt * 16 + mr) * 136 + kt * 32 + quad * 8];
      acc[nt] = __builtin_amdgcn_mfma_f32_16x16x32_bf16(af, bf, acc[nt], 0, 0, 0);
    }
  }
  // h3: per row (edge) reduce over 64 h2 dims (held across 16 lanes x 4 tiles)
#pragma unroll
  for (int r = 0; r < 4; ++r) {
    float o0 = 0.f, o1 = 0.f, o2 = 0.f;
#pragma unroll
    for (int nt = 0; nt < 4; ++nt) {
      float h = fmaxf(acc[nt][r] + b2r[nt], 0.f);
      o0 = fmaf(h, w3r[nt][0], o0);
      o1 = fmaf(h, w3r[nt][1], o1);
      o2 = fmaf(h, w3r[nt][2], o2);
    }
    o0 = rsum16(o0);
    o1 = rsum16(o1);
    o2 = rsum16(o2);
    if (mr == r) {
      size_t eg = (size_t)blockIdx.x * 64 + m0 + quad * 4 + r;
      out[eg * 3 + 0] = o0 + b3x;
      out[eg * 3 + 1] = o1 + b3y;
      out[eg * 3 + 2] = o2 + b3z;
    }
  }
}

// ---------------- host ------------------------------------------------------
extern "C" void kernel_launch(void* const* d_in, const int* in_sizes, int n_in,
                              void* d_out, int out_size, void* d_ws, size_t ws_size,
                              hipStream_t stream) {
  const float* A_dn = (const float*)d_in[0];
  const float* A_up = (const float*)d_in[1];
  const float* xDrDi = (const float*)d_in[2];
  const float* xDrG = (const float*)d_in[3];
  const float* xMDi = (const float*)d_in[4];
  const float* xMG = (const float*)d_in[5];
  const float* W80 = (const float*)d_in[6];
  const float* b80 = (const float*)d_in[7];
  const float* W64 = (const float*)d_in[8];
  const float* b64 = (const float*)d_in[9];
  const float* l1s = (const float*)d_in[10];
  const float* l1b = (const float*)d_in[11];
  const float* Wq = (const float*)d_in[12];
  const float* bq = (const float*)d_in[13];
  const float* Wk = (const float*)d_in[14];
  const float* bk = (const float*)d_in[15];
  const float* Wv = (const float*)d_in[16];
  const float* bv = (const float*)d_in[17];
  const float* Wo = (const float*)d_in[18];
  const float* bo = (const float*)d_in[19];
  const float* l2s = (const float*)d_in[20];
  const float* l2b = (const float*)d_in[21];
  const float* Wf1 = (const float*)d_in[22];
  const float* bf1 = (const float*)d_in[23];
  const float* Wf2 = (const float*)d_in[24];
  const float* bf2 = (const float*)d_in[25];
  const float* fs = (const float*)d_in[26];
  const float* fb = (const float*)d_in[27];
  const float* Wa = (const float*)d_in[28];
  // d_in[29] = ba (cancels in softmax)
  const float* Ws = (const float*)d_in[30];
  const float* bs = (const float*)d_in[31];
  const float* qs = (const float*)d_in[32];
  const float* Wm1 = (const float*)d_in[33];
  const float* bm1 = (const float*)d_in[34];
  const float* Wm2 = (const float*)d_in[35];
  const float* bm2 = (const float*)d_in[36];
  const float* Wm3 = (const float*)d_in[37];
  const float* bm3 = (const float*)d_in[38];
  const int* tre = (const int*)d_in[39];
  const int* vle = (const int*)d_in[40];
  (void)in_sizes; (void)n_in; (void)out_size; (void)ws_size;

  unsigned char* ws = (unsigned char*)d_ws;
  const size_t MB = 1024 * 1024;
  float* dm = (float*)(ws + 0);                       // 2 MB
  float* upf = (float*)(ws + 2 * MB);                 // 8 MB (8192,4,64)
  float* dnf = (float*)(ws + 10 * MB);                // 8 MB
  unsigned short* xt0 = (unsigned short*)(ws + 18 * MB);
  unsigned short* xtUa = (unsigned short*)(ws + 20 * MB);
  unsigned short* xtUb = (unsigned short*)(ws + 22 * MB);
  unsigned short* xtDa = (unsigned short*)(ws + 24 * MB);
  unsigned short* xtDb = (unsigned short*)(ws + 26 * MB);
  float* part = (float*)(ws + 28 * MB);               // 16 MB
  float* up_out = (float*)(ws + 44 * MB);             // 1 MB
  float* dn_out = (float*)(ws + 45 * MB);             // 1 MB
  float* acc = (float*)(ws + 46 * MB);                // 16 B
  float* drug = (float*)(ws + 46 * MB + 256);         // 256 KB
  float* meta = (float*)(ws + 46 * MB + 256 + 256 * 1024);
  float* Pd = (float*)(ws + 48 * MB);                 // 1 MB
  float* Pm = (float*)(ws + 49 * MB);                 // 3 MB

  // 1) four metapath encodings -> dm (one merged launch)
  enc2_kernel<0><<<512, 512, 0, stream>>>(
      xDrDi, xDrG, xMDi, xMG, dm, nullptr,
      W80, b80, l1s, l1b, Wq, bq, Wk, bk, Wv, bv, Wo, bo, l2s, l2b,
      Wf1, bf1, Wf2, bf2, fs, fb, Wa);

  // 2) dm -> slot0 feats + Xt0
  dm_to_xt<<<128, 256, 0, stream>>>(dm, upf, dnf, xt0);

  // 3) hop chains
  hop_matmul<<<128 * KC, 256, 0, stream>>>(A_dn, xt0, part);
  hop_finalize<<<128, 256, 0, stream>>>(part, upf + 64, xtUa);
  hop_matmul<<<128 * KC, 256, 0, stream>>>(A_dn, xtUa, part);
  hop_finalize<<<128, 256, 0, stream>>>(part, upf + 128, xtUb);
  hop_matmul<<<128 * KC, 256, 0, stream>>>(A_dn, xtUb, part);
  hop_finalize<<<128, 256, 0, stream>>>(part, upf + 192, xtUa);

  hop_matmul<<<128 * KC, 256, 0, stream>>>(A_up, xt0, part);
  hop_finalize<<<128, 256, 0, stream>>>(part, dnf + 64, xtDa);
  hop_matmul<<<128 * KC, 256, 0, stream>>>(A_up, xtDa, part);
  hop_finalize<<<128, 256, 0, stream>>>(part, dnf + 128, xtDb);
  hop_matmul<<<128 * KC, 256, 0, stream>>>(A_up, xtDb, part);
  hop_finalize<<<128, 256, 0, stream>>>(part, dnf + 192, xtDa);

  // 4) encoders on hop features (merged up+dn launch)
  enc2_kernel<1><<<512, 512, 0, stream>>>(
      upf, dnf, nullptr, nullptr, up_out, dn_out,
      W64, b64, l1s, l1b, Wq, bq, Wk, bk, Wv, bv, Wo, bo, l2s, l2b,
      Wf1, bf1, Wf2, bf2, fs, fb, Wa);

  // 5) semantic attention -> drug/meta embeddings
  zero_acc<<<1, 64, 0, stream>>>(acc);
  sem_reduce<<<2048, 256, 0, stream>>>(up_out, dn_out, Ws, bs, qs, acc);
  sem_combine<<<1024, 256, 0, stream>>>(up_out, dn_out, acc, drug, meta);

  // 6) edge MLP
  pdpm_kernel<<<NN, 128, 0, stream>>>(drug, meta, Wm1, bm1, Pd, Pm);
  edge_mlp2<<<ETOT / 64, 256, 0, stream>>>(tre, vle, Pd, Pm, Wm2, bm2, Wm3, bm3,
                                           (float*)d_out);
}